// Round 4
// baseline (243.320 us; speedup 1.0000x reference)
//
#include <hip/hip_runtime.h>
#include <hip/hip_bf16.h>
#include <stdint.h>

// Problem constants
#define D_MODEL 1024
#define NHEADS  16
#define DKH     64
#define BATCH   4
#define SEQ     2048
#define NTOK    (BATCH * SEQ)   // 8192

typedef unsigned short u16;
using bf16x8 = __attribute__((ext_vector_type(8))) short;   // 8 bf16 = 4 VGPR (MFMA A/B frag)
using f32x4  = __attribute__((ext_vector_type(4))) float;   // MFMA C/D frag

// async global->LDS, 16B per lane; LDS dest is wave-uniform base (+lane*16 by HW)
#define GLD16(g, l)                                                            \
  __builtin_amdgcn_global_load_lds(                                            \
      (const __attribute__((address_space(1))) void*)(g),                      \
      (__attribute__((address_space(3))) void*)(l), 16, 0, 0)

__device__ inline u16 f2bf(float f) {
  __hip_bfloat16 h = __float2bfloat16(f);
  return __builtin_bit_cast(u16, h);
}

// ---------------------------------------------------------------- fused converts
__global__ __launch_bounds__(256) void cvt_all(const float* __restrict__ x,
                                               const float* __restrict__ wq,
                                               const float* __restrict__ wk,
                                               const float* __restrict__ wv,
                                               const float* __restrict__ wo,
                                               u16* xb, u16* wqb, u16* wkb, u16* wvb, u16* wob) {
  const int XC = NTOK * D_MODEL / 4;      // 2097152
  const int WC = D_MODEL * D_MODEL / 4;   // 262144
  const int total = XC + 4 * WC;
  for (int i = blockIdx.x * 256 + threadIdx.x; i < total; i += gridDim.x * 256) {
    const float4* s; ushort4* d; int j;
    if (i < XC)              { s = (const float4*)x;  d = (ushort4*)xb;  j = i; }
    else if (i < XC + WC)    { s = (const float4*)wq; d = (ushort4*)wqb; j = i - XC; }
    else if (i < XC + 2*WC)  { s = (const float4*)wk; d = (ushort4*)wkb; j = i - XC - WC; }
    else if (i < XC + 3*WC)  { s = (const float4*)wv; d = (ushort4*)wvb; j = i - XC - 2*WC; }
    else                     { s = (const float4*)wo; d = (ushort4*)wob; j = i - XC - 3*WC; }
    float4 v = s[j];
    d[j] = make_ushort4(f2bf(v.x), f2bf(v.y), f2bf(v.z), f2bf(v.w));
  }
}

// ---------------------------------------------------------------- fused QKV projection
// A [NTOK,D] bf16; Bq/Bk/Bv [D,D] bf16 (nn.Linear layout, C = A*B^T).
// z=0: Q out, scaled 0.125*log2(e) (exp2-domain softmax). z=1: K. z=2: V transposed per-head.
__global__ __launch_bounds__(256) void gemm_qkv(const u16* __restrict__ A,
                                                const u16* __restrict__ Bq,
                                                const u16* __restrict__ Bk,
                                                const u16* __restrict__ Bv,
                                                u16* __restrict__ Qo,
                                                u16* __restrict__ Ko,
                                                u16* __restrict__ Vo) {
  __shared__ u16 As[128 * 64];
  __shared__ u16 Bs[128 * 64];
  const int z = blockIdx.z;
  const u16* __restrict__ Bp = z == 0 ? Bq : (z == 1 ? Bk : Bv);
  const int t = threadIdx.x, lane = t & 63, wave = t >> 6;
  const int wr = wave >> 1, wc = wave & 1;
  const int frow = lane & 15, fk = (lane >> 4) * 8;
  const int bM = blockIdx.y * 128, bN = blockIdx.x * 128;

  f32x4 acc[4][4] = {};

  for (int k0 = 0; k0 < D_MODEL; k0 += 64) {
    __syncthreads();
#pragma unroll
    for (int p = 0; p < 4; ++p) {
      int chunk = p * 256 + t;
      int r = chunk >> 3, cc = chunk & 7;
      GLD16(A + (size_t)(bM + r) * D_MODEL + k0 + cc * 8, As + (size_t)(p * 256 + (t & ~63)) * 8);
      GLD16(Bp + (size_t)(bN + r) * D_MODEL + k0 + cc * 8, Bs + (size_t)(p * 256 + (t & ~63)) * 8);
    }
    __syncthreads();

    bf16x8 a[2][4], b[2][4];
#pragma unroll
    for (int kk = 0; kk < 2; ++kk) {
#pragma unroll
      for (int m = 0; m < 4; ++m)
        a[kk][m] = *(const bf16x8*)&As[(wr * 64 + m * 16 + frow) * 64 + kk * 32 + fk];
#pragma unroll
      for (int n = 0; n < 4; ++n)
        b[kk][n] = *(const bf16x8*)&Bs[(wc * 64 + n * 16 + frow) * 64 + kk * 32 + fk];
    }
#pragma unroll
    for (int kk = 0; kk < 2; ++kk)
#pragma unroll
      for (int m = 0; m < 4; ++m)
#pragma unroll
        for (int n = 0; n < 4; ++n)
          acc[m][n] = __builtin_amdgcn_mfma_f32_16x16x32_bf16(a[kk][m], b[kk][n], acc[m][n], 0, 0, 0);
  }

  const int r0 = bM + wr * 64 + (lane >> 4) * 4;
  const int c0 = bN + wc * 64 + (lane & 15);
  if (z == 2) {
#pragma unroll
    for (int m = 0; m < 4; ++m)
#pragma unroll
      for (int n = 0; n < 4; ++n) {
        int r = r0 + m * 16;   // token (4-aligned, j stays in one batch)
        int cc = c0 + n * 16;  // d_model col
        size_t off = ((size_t)(r >> 11) * D_MODEL + cc) * SEQ + (r & (SEQ - 1));
        *(ushort4*)(Vo + off) = make_ushort4(f2bf(acc[m][n][0]), f2bf(acc[m][n][1]),
                                             f2bf(acc[m][n][2]), f2bf(acc[m][n][3]));
      }
  } else {
    u16* C = z ? Ko : Qo;
    const float sc = z ? 1.0f : 0.18033688f;  // (1/8)*log2(e): softmax in exp2 domain
#pragma unroll
    for (int m = 0; m < 4; ++m)
#pragma unroll
      for (int n = 0; n < 4; ++n)
#pragma unroll
        for (int j = 0; j < 4; ++j)
          C[(size_t)(r0 + m * 16 + j) * D_MODEL + (c0 + n * 16)] = f2bf(acc[m][n][j] * sc);
  }
}

// ---------------------------------------------------------------- output projection C = A*B^T, f32 out
__global__ __launch_bounds__(256) void gemm_out(const u16* __restrict__ A,
                                                const u16* __restrict__ B,
                                                float* __restrict__ C) {
  __shared__ u16 As[128 * 64];
  __shared__ u16 Bs[128 * 64];
  const int t = threadIdx.x, lane = t & 63, wave = t >> 6;
  const int wr = wave >> 1, wc = wave & 1;
  const int frow = lane & 15, fk = (lane >> 4) * 8;
  const int bM = blockIdx.y * 128, bN = blockIdx.x * 128;

  f32x4 acc[4][4] = {};

  for (int k0 = 0; k0 < D_MODEL; k0 += 64) {
    __syncthreads();
#pragma unroll
    for (int p = 0; p < 4; ++p) {
      int chunk = p * 256 + t;
      int r = chunk >> 3, cc = chunk & 7;
      GLD16(A + (size_t)(bM + r) * D_MODEL + k0 + cc * 8, As + (size_t)(p * 256 + (t & ~63)) * 8);
      GLD16(B + (size_t)(bN + r) * D_MODEL + k0 + cc * 8, Bs + (size_t)(p * 256 + (t & ~63)) * 8);
    }
    __syncthreads();

    bf16x8 a[2][4], b[2][4];
#pragma unroll
    for (int kk = 0; kk < 2; ++kk) {
#pragma unroll
      for (int m = 0; m < 4; ++m)
        a[kk][m] = *(const bf16x8*)&As[(wr * 64 + m * 16 + frow) * 64 + kk * 32 + fk];
#pragma unroll
      for (int n = 0; n < 4; ++n)
        b[kk][n] = *(const bf16x8*)&Bs[(wc * 64 + n * 16 + frow) * 64 + kk * 32 + fk];
    }
#pragma unroll
    for (int kk = 0; kk < 2; ++kk)
#pragma unroll
      for (int m = 0; m < 4; ++m)
#pragma unroll
        for (int n = 0; n < 4; ++n)
          acc[m][n] = __builtin_amdgcn_mfma_f32_16x16x32_bf16(a[kk][m], b[kk][n], acc[m][n], 0, 0, 0);
  }

  const int r0 = bM + wr * 64 + (lane >> 4) * 4;
  const int c0 = bN + wc * 64 + (lane & 15);
#pragma unroll
  for (int m = 0; m < 4; ++m)
#pragma unroll
    for (int n = 0; n < 4; ++n)
#pragma unroll
      for (int j = 0; j < 4; ++j)
        C[(size_t)(r0 + m * 16 + j) * D_MODEL + (c0 + n * 16)] = acc[m][n][j];
}

// ---------------------------------------------------------------- flash attention (causal)
// Q (pre-scaled 0.125*log2e), K: bf16 [NTOK, D_MODEL]; Vt: bf16 [B*H*64][SEQ];
// O: bf16 [NTOK, D_MODEL].
// Block = paired q-tiles (H=15-p heavy, L=p light) of one (b,h): 8 waves, waves 0-3 -> H,
// waves 4-7 -> L. One KV sweep stages each K/V tile once for both -> balanced blocks
// (136 wave-iters each) and halved staging traffic. Softmax in exp2 domain, defer-max.
__global__ __launch_bounds__(512) void attn_fwd(const u16* __restrict__ Q,
                                                const u16* __restrict__ K,
                                                const u16* __restrict__ Vt,
                                                u16* __restrict__ O) {
  __shared__ u16 Kl[2][64 * 64];   // 16 KB (dbuf)
  __shared__ u16 Vl[2][64 * 64];   // 16 KB (dbuf)
  __shared__ u16 Pl[8][16 * 64];   // 16 KB -> 48 KB total

  const int t = threadIdx.x, lane = t & 63, wave = t >> 6;
  const int c = lane & 15, g = lane >> 4;
  const int bh = blockIdx.x & 63;           // same-bh blocks: consecutive mod 64 -> same XCD
  const int jj = blockIdx.x >> 6;           // 0..7
  const int p = jj < 4 ? jj : 11 - jj;      // balances {i,i+256} CU pairs
  const int qtile = (wave < 4) ? (15 - p) : p;
  const size_t rowbase = (size_t)(bh >> 4) * SEQ;
  const int hcol = (bh & 15) * DKH;
  const int qw = qtile * 128 + (wave & 3) * 32;
  u16* pw = Pl[wave];
  const int nit = (15 - p) * 2 + 2;         // KV tiles for the heavy q-tile

  auto stage = [&](int buf, int kv0) {
    int r = t >> 3, cc = t & 7;
    int cs = cc ^ (r & 7);  // pre-swizzled global source; LDS linear
    GLD16(K + (rowbase + kv0 + r) * D_MODEL + hcol + cs * 8,
          &Kl[buf][(size_t)(t & ~63) * 8]);
    GLD16(Vt + ((size_t)bh * DKH + r) * SEQ + kv0 + cs * 8,
          &Vl[buf][(size_t)(t & ~63) * 8]);
  };

  stage(0, 0);

  bf16x8 qf[2][2];
#pragma unroll
  for (int m = 0; m < 2; ++m)
#pragma unroll
    for (int kk = 0; kk < 2; ++kk)
      qf[m][kk] = *(const bf16x8*)&Q[(rowbase + qw + m * 16 + c) * D_MODEL + hcol + kk * 32 + g * 8];

  f32x4 ot[4][2] = {};              // O^T[d_local][q]
  float mstate[2] = {-__builtin_inff(), -__builtin_inff()};
  float lstate[2] = {0.f, 0.f};

  __syncthreads();
  int cur = 0;
  for (int it = 0; it < nit; ++it) {
    const int kv0 = it * 64;
    if (it + 1 < nit) stage(cur ^ 1, kv0 + 64);

    if (kv0 <= qw + 31) {  // wave-uniform causal participation (light waves retire early)
      // ---- S^T = K Q^T (exp2-domain scores)
      bf16x8 kf[4][2];
#pragma unroll
      for (int n = 0; n < 4; ++n)
#pragma unroll
        for (int kk = 0; kk < 2; ++kk)
          kf[n][kk] = *(const bf16x8*)&Kl[cur][(n * 16 + c) * 64 + (((g + 4 * kk) ^ (c & 7)) * 8)];
      f32x4 s[4][2] = {};
      __builtin_amdgcn_s_setprio(1);
#pragma unroll
      for (int kk = 0; kk < 2; ++kk)
#pragma unroll
        for (int n = 0; n < 4; ++n)
#pragma unroll
          for (int m = 0; m < 2; ++m)
            s[n][m] = __builtin_amdgcn_mfma_f32_16x16x32_bf16(kf[n][kk], qf[m][kk], s[n][m], 0, 0, 0);
      __builtin_amdgcn_s_setprio(0);

      // V^T fragments early: ds_read latency hides under softmax VALU
      bf16x8 vf[4][2];
#pragma unroll
      for (int d = 0; d < 4; ++d)
#pragma unroll
        for (int kk = 0; kk < 2; ++kk)
          vf[d][kk] = *(const bf16x8*)&Vl[cur][(d * 16 + c) * 64 + (((g + 4 * kk) ^ (c & 7)) * 8)];

      const bool need_mask = (kv0 + 63 > qw);
#pragma unroll
      for (int m = 0; m < 2; ++m) {
        const int qg = qw + m * 16 + c;
        if (need_mask) {
#pragma unroll
          for (int n = 0; n < 4; ++n)
#pragma unroll
            for (int jj2 = 0; jj2 < 4; ++jj2)
              if (kv0 + n * 16 + g * 4 + jj2 > qg) s[n][m][jj2] = -__builtin_inff();
        }
        float pmax = fmaxf(fmaxf(s[0][m][0], s[0][m][1]), fmaxf(s[0][m][2], s[0][m][3]));
#pragma unroll
        for (int n = 1; n < 4; ++n)
          pmax = fmaxf(pmax, fmaxf(fmaxf(s[n][m][0], s[n][m][1]), fmaxf(s[n][m][2], s[n][m][3])));
        pmax = fmaxf(pmax, __shfl_xor(pmax, 16));
        pmax = fmaxf(pmax, __shfl_xor(pmax, 32));
        // defer-max (T13), log2 domain: P bounded by 2^11.54 = e^8
        if (__any(pmax > mstate[m] + 11.5416f)) {
          float mnew = fmaxf(mstate[m], pmax);
          float al = exp2f(mstate[m] - mnew);  // first tile: exp2(-inf)=0
          mstate[m] = mnew;
          lstate[m] *= al;
#pragma unroll
          for (int d = 0; d < 4; ++d)
#pragma unroll
            for (int jj2 = 0; jj2 < 4; ++jj2) ot[d][m][jj2] *= al;
        }
        const float mm = mstate[m];
        float lsum = 0.f;
#pragma unroll
        for (int n = 0; n < 4; ++n) {
          float p0 = exp2f(s[n][m][0] - mm);
          float p1 = exp2f(s[n][m][1] - mm);
          float p2 = exp2f(s[n][m][2] - mm);
          float p3 = exp2f(s[n][m][3] - mm);
          lsum += (p0 + p1) + (p2 + p3);
          // P[q=c][k=n*16+g*4+jj], 16B-chunk XOR swizzle by row&7
          *(ushort4*)&pw[c * 64 + (((n * 2 + (g >> 1)) ^ (c & 7)) * 8) + (g & 1) * 4] =
              make_ushort4(f2bf(p0), f2bf(p1), f2bf(p2), f2bf(p3));
        }
        lsum += __shfl_xor(lsum, 16);
        lsum += __shfl_xor(lsum, 32);
        lstate[m] += lsum;

        // ---- O^T[.,m] += V^T P^T (wave-private LDS roundtrip; in-order DS ops, no barrier)
        bf16x8 pf[2];
#pragma unroll
        for (int kk = 0; kk < 2; ++kk)
          pf[kk] = *(const bf16x8*)&pw[c * 64 + (((g + 4 * kk) ^ (c & 7)) * 8)];
        __builtin_amdgcn_s_setprio(1);
#pragma unroll
        for (int kk = 0; kk < 2; ++kk)
#pragma unroll
          for (int d = 0; d < 4; ++d)
            ot[d][m] = __builtin_amdgcn_mfma_f32_16x16x32_bf16(vf[d][kk], pf[kk], ot[d][m], 0, 0, 0);
        __builtin_amdgcn_s_setprio(0);
      }
    }
    __syncthreads();
    cur ^= 1;
  }

  // ---- epilogue: O[q][d] = O^T/l
#pragma unroll
  for (int m = 0; m < 2; ++m) {
    float inv = 1.0f / lstate[m];
#pragma unroll
    for (int d = 0; d < 4; ++d) {
      ushort4 o4 = make_ushort4(f2bf(ot[d][m][0] * inv), f2bf(ot[d][m][1] * inv),
                                f2bf(ot[d][m][2] * inv), f2bf(ot[d][m][3] * inv));
      *(ushort4*)&O[(rowbase + qw + m * 16 + c) * D_MODEL + hcol + d * 16 + g * 4] = o4;
    }
  }
}

// ---------------------------------------------------------------- launch
extern "C" void kernel_launch(void* const* d_in, const int* in_sizes, int n_in,
                              void* d_out, int out_size, void* d_ws, size_t ws_size,
                              hipStream_t stream) {
  const float* x  = (const float*)d_in[0];
  const float* Wq = (const float*)d_in[1];
  const float* Wk = (const float*)d_in[2];
  const float* Wv = (const float*)d_in[3];
  const float* Wo = (const float*)d_in[4];
  float* out = (float*)d_out;

  u16* ws  = (u16*)d_ws;
  u16* xb  = ws;
  u16* wqb = xb + (size_t)NTOK * D_MODEL;
  u16* wkb = wqb + (size_t)D_MODEL * D_MODEL;
  u16* wvb = wkb + (size_t)D_MODEL * D_MODEL;
  u16* wob = wvb + (size_t)D_MODEL * D_MODEL;
  u16* Qb  = wob + (size_t)D_MODEL * D_MODEL;
  u16* Kb  = Qb + (size_t)NTOK * D_MODEL;
  u16* Vb  = Kb + (size_t)NTOK * D_MODEL;   // per-head V^T [B*H*64][SEQ]
  u16* Ob  = xb;  // reuse x's bf16 buffer after projections

  cvt_all<<<2048, 256, 0, stream>>>(x, Wq, Wk, Wv, Wo, xb, wqb, wkb, wvb, wob);

  gemm_qkv<<<dim3(D_MODEL / 128, NTOK / 128, 3), 256, 0, stream>>>(xb, wqb, wkb, wvb, Qb, Kb, Vb);

  attn_fwd<<<dim3(8 * 64), 512, 0, stream>>>(Qb, Kb, Vb, Ob);

  gemm_out<<<dim3(D_MODEL / 128, NTOK / 128), 256, 0, stream>>>(Ob, wob, out);
}